// Round 5
// baseline (111.242 us; speedup 1.0000x reference)
//
#include <hip/hip_runtime.h>
#include <math.h>

// NetVLAD: B=8, N=2048, D=128, K=64, fp32 in/out.
#define BB 8
#define NN 2048
#define DD 128
#define KK 64
#define PP 64            // blocks per batch for K1 (512 blocks = 2/CU)
#define NPB (NN / PP)    // 32 descriptors per block

// ---------------------------------------------------------------------------
// Cross-lane reduction helpers.
// DPP adds run on the VALU pipe (not DS) — round 1/2 k1 was DS-pipe-bound
// (ds_read + shfl's ds_swizzle ~1145 LDS cyc/wave/iter).
// dpp_ctrl must be an integer-constant-expression at the builtin call site,
// hence the template parameter.
// quad_perm [1,0,3,2]=0xB1 (xor1), [2,3,0,1]=0x4E (xor2),
// ROW_HALF_MIRROR=0x141 (pairs quads), ROW_MIRROR=0x140 (pairs 8-halves):
// after the 4 steps every lane in a 16-row holds the 16-lane sum.
// ---------------------------------------------------------------------------
template <int CTRL>
__device__ __forceinline__ float dppadd(float x) {
    return x + __int_as_float(__builtin_amdgcn_update_dpp(
        0, __float_as_int(x), CTRL, 0xF, 0xF, true));
}
__device__ __forceinline__ float row16sum(float x) {
    x = dppadd<0xB1>(x);   // quad_perm [1,0,3,2]: xor1 within quad
    x = dppadd<0x4E>(x);   // quad_perm [2,3,0,1]: xor2 within quad
    x = dppadd<0x141>(x);  // ROW_HALF_MIRROR: combine quads within 8
    x = dppadd<0x140>(x);  // ROW_MIRROR: combine 8-halves within 16
    return x;
}
__device__ __forceinline__ float sum32(float x) {  // 32-lane group sum
    x = row16sum(x);
    // xor16 within 32-lane group: one ds_swizzle (BitMode 0x401F)
    return x + __int_as_float(
        __builtin_amdgcn_ds_swizzle(__float_as_int(x), 0x401F));
}
__device__ __forceinline__ float dot4(float4 a, float4 b) {
    return a.x*b.x + a.y*b.y + a.z*b.z + a.w*b.w;
}

// ---------------------------------------------------------------------------
// K1: fused normalize + assignment softmax + weighted accumulation.
// Grid: BB*PP = 512 blocks of 256 threads.
// Thread t: kq = t>>4 in [0,16) owns 4 k's (k = kq*4+kk);
//           pr = t&15 owns d-chunks {pr*4..pr*4+3} and {64+pr*4..}.
// pr is lane%16 -> every dot/cn2 reduction is a 16-row DPP reduction.
// NOTE: a = e*rsum is UNIFORM across the 16 pr lanes, so each lane's sA
// already holds the full sum over descriptors — the epilogue must NOT
// row16sum it (round-4 bug: 16x-inflated sumA -> absmax 1.07e-2).
// ---------------------------------------------------------------------------
__global__ __launch_bounds__(256, 4) void netvlad_k1(
    const float* __restrict__ x, const float* __restrict__ cent,
    float* __restrict__ part_acc, float* __restrict__ part_sA)
{
    const int b    = blockIdx.x >> 6;    // / PP
    const int p    = blockIdx.x & 63;    // % PP
    const int t    = threadIdx.x;
    const int kq   = t >> 4;             // 0..15
    const int pr   = t & 15;             // 0..15
    const int wave = t >> 6;
    const int lane = t & 63;
    const int half = (t >> 5) & 1;
    const int hl   = t & 31;

    __shared__ float4 xn4[8][32];   // 4 KB: normalized descriptors (8 rows x 128 d)
    __shared__ float  eL[4][KK];    // 1 KB: exp values for current 4-desc group
    __shared__ __align__(16) float rsum[4];  // reciprocal softmax denominators

    // Centroid fragments in registers + per-k ||c||^2 (full 128-d via DPP).
    float4 c0[4], c1[4];
    float cn2[4];
    #pragma unroll
    for (int kk = 0; kk < 4; ++kk) {
        const int k = kq * 4 + kk;
        c0[kk] = *(const float4*)(cent + k * DD + pr * 4);
        c1[kk] = *(const float4*)(cent + k * DD + 64 + pr * 4);
        cn2[kk] = row16sum(dot4(c0[kk], c0[kk]) + dot4(c1[kk], c1[kk]));
    }

    float4 acc0[4], acc1[4];
    float sA[4];
    #pragma unroll
    for (int kk = 0; kk < 4; ++kk) {
        acc0[kk] = make_float4(0.f, 0.f, 0.f, 0.f);
        acc1[kk] = make_float4(0.f, 0.f, 0.f, 0.f);
        sA[kk] = 0.f;
    }

    const float* xb = x + ((size_t)b * NN + (size_t)p * NPB) * DD;

    for (int outer = 0; outer < NPB / 8; ++outer) {
        __syncthreads();  // xn4 safe to overwrite (prev Phase C done)

        // ---- Phase A: load + L2-normalize 8 descriptors (half-wave each)
        {
            const int r = (wave << 1) | half;   // row 0..7
            const float* xp = xb + (size_t)(outer * 8 + r) * DD + hl * 4;
            float4 v = *(const float4*)xp;
            float ss = sum32(v.x*v.x + v.y*v.y + v.z*v.z + v.w*v.w);
            const float rn = 1.0f / fmaxf(sqrtf(ss), 1e-12f);
            xn4[r][hl] = make_float4(v.x*rn, v.y*rn, v.z*rn, v.w*rn);
        }
        __syncthreads();

        for (int sub = 0; sub < 2; ++sub) {
            const int r0 = sub * 4;

            // ---- Phase B: dots + exp. assign ∝ exp(||c||^2 - 2 xn·c)
            float e[4][4];
            #pragma unroll
            for (int i = 0; i < 4; ++i) {
                const float4 u0 = xn4[r0 + i][pr];
                const float4 u1 = xn4[r0 + i][16 + pr];
                #pragma unroll
                for (int kk = 0; kk < 4; ++kk) {
                    float S = dot4(u0, c0[kk]) + dot4(u1, c1[kk]);
                    S = row16sum(S);
                    e[i][kk] = __expf(cn2[kk] - 2.0f * S);
                }
                if (pr == 0)
                    *(float4*)(&eL[i][kq * 4]) =
                        make_float4(e[i][0], e[i][1], e[i][2], e[i][3]);
            }
            __syncthreads();

            // ---- softmax denominators: wave w reduces row w (64 values)
            {
                const float2 ev = *(const float2*)(&eL[wave][(lane & 31) * 2]);
                const float s = sum32(ev.x + ev.y);
                if (lane == 0) rsum[wave] = 1.0f / s;
            }
            __syncthreads();

            // ---- Phase C: accumulate assign * xn into register tile
            const float4 rv = *(const float4*)rsum;
            #pragma unroll
            for (int i = 0; i < 4; ++i) {
                const float4 u0 = xn4[r0 + i][pr];
                const float4 u1 = xn4[r0 + i][16 + pr];
                const float ri = (&rv.x)[i];
                #pragma unroll
                for (int kk = 0; kk < 4; ++kk) {
                    const float a = e[i][kk] * ri;
                    sA[kk] += a;
                    acc0[kk].x += a*u0.x; acc0[kk].y += a*u0.y;
                    acc0[kk].z += a*u0.z; acc0[kk].w += a*u0.w;
                    acc1[kk].x += a*u1.x; acc1[kk].y += a*u1.y;
                    acc1[kk].z += a*u1.z; acc1[kk].w += a*u1.w;
                }
            }
        }
    }

    // ---- epilogue: sA is already the full per-k sum in every pr lane
    // (a is uniform across pr) — write pr==0's copy, NO cross-pr reduction.
    if (pr == 0) {
        #pragma unroll
        for (int kk = 0; kk < 4; ++kk)   // layout [b][k][p] for coalesced k2
            part_sA[((size_t)b * KK + kq * 4 + kk) * PP + p] = sA[kk];
    }
    const size_t base = (size_t)(b * PP + p) * KK * DD;
    #pragma unroll
    for (int kk = 0; kk < 4; ++kk) {
        const int k = kq * 4 + kk;
        *(float4*)(part_acc + base + k * DD + pr * 4)      = acc0[kk];
        *(float4*)(part_acc + base + k * DD + 64 + pr * 4) = acc1[kk];
    }
}

// ---------------------------------------------------------------------------
// K2: reduce 64 partials per (b,k), subtract c*sumA, intra-normalize, apply
// global scale. Every intra-normalized row has sumsq == 1 (to ~1e-7), so the
// global norm is sqrt(K)=8 exactly — fold 0.125 here, no third pass.
// Grid: BB*KK = 512 blocks of 128 threads.
// ---------------------------------------------------------------------------
__global__ __launch_bounds__(128) void netvlad_k2(
    const float* __restrict__ cent, const float* __restrict__ part_acc,
    const float* __restrict__ part_sA, float* __restrict__ out)
{
    const int b  = blockIdx.x >> 6;
    const int k  = blockIdx.x & 63;
    const int t  = threadIdx.x;
    const int d4 = t & 31;
    const int ps = t >> 5;

    __shared__ float sAL;
    if (t < 64) {
        float sA = part_sA[((size_t)b * KK + k) * PP + t];  // coalesced
        #pragma unroll
        for (int m = 1; m < 64; m <<= 1) sA += __shfl_xor(sA, m);
        if (t == 0) sAL = sA;
    }

    // each thread sums 16 p's of its float4 column
    float4 acc = make_float4(0.f, 0.f, 0.f, 0.f);
    const float* basep = part_acc + ((size_t)(b * PP) * KK + k) * DD + d4 * 4;
    #pragma unroll 8
    for (int pp = 0; pp < 16; ++pp) {
        const float4 v = *(const float4*)(basep + (size_t)(ps * 16 + pp) * KK * DD);
        acc.x += v.x; acc.y += v.y; acc.z += v.z; acc.w += v.w;
    }

    __shared__ float4 red[4][32];
    red[ps][d4] = acc;
    __syncthreads();
    const float sAt = sAL;

    if (t < 32) {
        float4 v = red[0][t];
        #pragma unroll
        for (int s = 1; s < 4; ++s) {
            v.x += red[s][t].x; v.y += red[s][t].y;
            v.z += red[s][t].z; v.w += red[s][t].w;
        }
        const float4 c = *(const float4*)(cent + k * DD + t * 4);
        v.x -= c.x * sAt; v.y -= c.y * sAt; v.z -= c.z * sAt; v.w -= c.w * sAt;

        float ss = v.x*v.x + v.y*v.y + v.z*v.z + v.w*v.w;
        #pragma unroll
        for (int m = 1; m < 32; m <<= 1) ss += __shfl_xor(ss, m);
        const float rn = 0.125f / fmaxf(sqrtf(ss), 1e-12f);
        v.x *= rn; v.y *= rn; v.z *= rn; v.w *= rn;
        *(float4*)(out + ((size_t)b * KK + k) * DD + t * 4) = v;
    }
}

extern "C" void kernel_launch(void* const* d_in, const int* in_sizes, int n_in,
                              void* d_out, int out_size, void* d_ws, size_t ws_size,
                              hipStream_t stream) {
    const float* x    = (const float*)d_in[0];   // [8, 2048, 128] fp32
    const float* cent = (const float*)d_in[1];   // [64, 128] fp32
    float* out = (float*)d_out;                  // [8, 8192] fp32

    char* ws = (char*)d_ws;
    float* part_sA  = (float*)ws;                 // 8*64*64 fp32 = 128 KB
    float* part_acc = (float*)(ws + (1 << 18));   // 8*64*64*128 fp32 = 16 MB

    netvlad_k1<<<dim3(BB * PP), dim3(256), 0, stream>>>(x, cent, part_acc, part_sA);
    netvlad_k2<<<dim3(BB * KK), dim3(128), 0, stream>>>(cent, part_acc, part_sA, out);
}